// Round 9
// baseline (432.309 us; speedup 1.0000x reference)
//
#include <hip/hip_runtime.h>
#include <hip/hip_bf16.h>
#include <math.h>

#define NUM_USERS  100000
#define NUM_ITEMS  50000
#define N_NODES    150000
#define EMBED_DIM  64
#define NUM_EDGES  1250000
#define MLP_HID    32
#define SCAN_B     1024
#define SCAN_NB    ((N_NODES + SCAN_B - 1) / SCAN_B)   // 147
#define NPW        4                                   // nodes per wave
#define PAD(x)     (((x) + 15) & ~15)                  // segment pad to 16

// ---------------------------------------------------------------------------
// Phase 1: count only. Fire-and-forget atomics (no return value -> no wave
// stall on latency), 4 edges/thread via int4 col load.
// ---------------------------------------------------------------------------
__global__ void count4(const int* __restrict__ edge_index,
                       int* __restrict__ cnt) {
    int t = blockIdx.x * blockDim.x + threadIdx.x;
    int e = 4 * t;                          // NUM_EDGES % 4 == 0
    if (e >= NUM_EDGES) return;
    int4 c = *(const int4*)(edge_index + NUM_EDGES + e);
    atomicAdd(&cnt[c.x], 1);
    atomicAdd(&cnt[c.y], 1);
    atomicAdd(&cnt[c.z], 1);
    atomicAdd(&cnt[c.w], 1);
}

// ---------------------------------------------------------------------------
// Device-wide exclusive scan of PAD16(cnt) -> row_ptr (+ wp copy), 3 phases.
// ---------------------------------------------------------------------------
__global__ void scan_partial(const int* __restrict__ cnt,
                             int* __restrict__ part) {
    __shared__ int s[SCAN_B];
    int tid = threadIdx.x;
    int i = blockIdx.x * SCAN_B + tid;
    s[tid] = (i < N_NODES) ? PAD(cnt[i]) : 0;
    __syncthreads();
#pragma unroll
    for (int off = SCAN_B / 2; off > 0; off >>= 1) {
        if (tid < off) s[tid] += s[tid + off];
        __syncthreads();
    }
    if (tid == 0) part[blockIdx.x] = s[0];
}

__global__ void scan_offsets(const int* __restrict__ part,
                             int* __restrict__ base_off) {
    __shared__ int s[256];
    int tid = threadIdx.x;
    int v = (tid < SCAN_NB) ? part[tid] : 0;
    s[tid] = v;
    __syncthreads();
#pragma unroll
    for (int off = 1; off < 256; off <<= 1) {
        int t = (tid >= off) ? s[tid - off] : 0;
        __syncthreads();
        s[tid] += t;
        __syncthreads();
    }
    if (tid < SCAN_NB) base_off[tid] = s[tid] - v;   // exclusive
}

__global__ void scan_apply(const int* __restrict__ cnt,
                           const int* __restrict__ base_off,
                           int* __restrict__ row_ptr,
                           int* __restrict__ wp) {
    __shared__ int s[SCAN_B];
    int tid = threadIdx.x;
    int i = blockIdx.x * SCAN_B + tid;
    int v = (i < N_NODES) ? PAD(cnt[i]) : 0;
    s[tid] = v;
    __syncthreads();
    for (int off = 1; off < SCAN_B; off <<= 1) {
        int t = (tid >= off) ? s[tid - off] : 0;
        __syncthreads();
        s[tid] += t;
        __syncthreads();
    }
    if (i < N_NODES) {
        int v0 = s[tid] - v + base_off[blockIdx.x];
        row_ptr[i] = v0;
        wp[i] = v0;                     // write-pointer copy for mlp_scatter
    }
    if (i == N_NODES - 1) row_ptr[N_NODES] = s[tid] + base_off[blockIdx.x];
}

// ---------------------------------------------------------------------------
// Phase 2: MLP + slot claim + DIRECT pair scatter.
// pos = atomicAdd(&wp[c],1) issued BEFORE the MLP: its ~600-cycle return
// latency hides under the ~300-instr MLP.  Eliminates rank/epair/perm and
// pair_build's random gather entirely.
// ---------------------------------------------------------------------------
__global__ void mlp_scatter(const float* __restrict__ edge_attr,
                            const float* __restrict__ ew,
                            const float* __restrict__ w1,
                            const float* __restrict__ b1,
                            const float* __restrict__ w2,
                            const float* __restrict__ b2,
                            const int*   __restrict__ edge_index,
                            int*  __restrict__ wp,
                            int2* __restrict__ csr_pair) {
    __shared__ float w1s[8 * MLP_HID];
    __shared__ float b1s[MLP_HID];
    __shared__ float w2s[MLP_HID];
    int tid = threadIdx.x;
    if (tid < 8 * MLP_HID) w1s[tid] = w1[tid];
    if (tid < MLP_HID) { b1s[tid] = b1[tid]; w2s[tid] = w2[tid]; }
    __syncthreads();

    int e = blockIdx.x * blockDim.x + tid;
    if (e >= NUM_EDGES) return;

    int c = edge_index[NUM_EDGES + e];
    int pos = atomicAdd(&wp[c], 1);      // issued early; consumed at the end

    float ef[8];
#pragma unroll
    for (int k = 0; k < 7; ++k) ef[k] = edge_attr[e * 7 + k];
    ef[7] = ew[e];

    float s = b2[0];
#pragma unroll
    for (int j = 0; j < MLP_HID; ++j) {
        float h = b1s[j];
#pragma unroll
        for (int k = 0; k < 8; ++k) h = fmaf(ef[k], w1s[k * MLP_HID + j], h);
        h = fmaxf(h, 0.0f);
        s = fmaf(h, w2s[j], s);
    }
    float w = 1.0f / (1.0f + expf(-s));

    int2 pr;
    pr.x = edge_index[e];                // src row
    pr.y = __float_as_int(w);            // RAW weight
    csr_pair[pos] = pr;                  // the single random scatter
}

// ---------------------------------------------------------------------------
// Streaming per-node pass: deg = sum of raw w over REAL entries; writes
// dinv, dinv2 = dinv^2, rd = 1/dinv; zeroes pad slots [re,e) and the
// 64-pair tail after the last node (for propagate prefetch overrun).
// ---------------------------------------------------------------------------
__global__ void degpad(const int* __restrict__ row_ptr,
                       const int* __restrict__ cnt,
                       int2* __restrict__ csr_pair,
                       float* __restrict__ dinv,
                       float* __restrict__ dinv2,
                       float* __restrict__ rd) {
    int t = blockIdx.x * blockDim.x + threadIdx.x;
    int node = t >> 4;
    int lane = t & 15;
    if (node >= N_NODES) return;
    int s  = row_ptr[node];
    int e  = row_ptr[node + 1];
    int re = s + cnt[node];
    float sum = 0.0f;
    for (int j = s + lane; j < re; j += 16)
        sum += __int_as_float(csr_pair[j].y);
    int2 z; z.x = 0; z.y = 0;
    for (int j = re + lane; j < e; j += 16) csr_pair[j] = z;
    sum += __shfl_xor(sum, 8);
    sum += __shfl_xor(sum, 4);
    sum += __shfl_xor(sum, 2);
    sum += __shfl_xor(sum, 1);
    if (lane == 0) {
        float dv = (sum > 0.0f) ? rsqrtf(fmaxf(sum, 1e-30f)) : 0.0f;
        dinv[node]  = dv;
        dinv2[node] = dv * dv;
        rd[node]    = (dv > 0.0f) ? (1.0f / dv) : 0.0f;
    }
    if (node == N_NODES - 1) {
        for (int q = lane; q < 64; q += 16) csr_pair[e + q] = z;
    }
}

// ---------------------------------------------------------------------------
// build x0 (f32, parked in the OUTPUT buffer for the final merge) and
// y0 = dinv * x0 (bf16, the propagation state).
// ---------------------------------------------------------------------------
__global__ void init_x(const float* __restrict__ user_w,
                       const float* __restrict__ artist_w,
                       const float* __restrict__ album_w,
                       const float* __restrict__ audio,
                       const int*   __restrict__ artist_ids,
                       const int*   __restrict__ album_ids,
                       const float* __restrict__ dinv,
                       float* __restrict__ x0out,
                       unsigned short* __restrict__ y0) {
    int t = blockIdx.x * blockDim.x + threadIdx.x;
    int row = t >> 6;
    int lane = t & 63;
    if (row >= N_NODES) return;

    float v;
    if (row < NUM_USERS) {
        v = user_w[row * EMBED_DIM + lane];
    } else {
        int r = row - NUM_USERS;
        int ar = artist_ids[r];
        int al = album_ids[r];
        v = audio[r * EMBED_DIM + lane]
          + 0.5f * (artist_w[ar * EMBED_DIM + lane] + album_w[al * EMBED_DIM + lane]);
    }
    float ss = v * v;
#pragma unroll
    for (int off = 32; off > 0; off >>= 1) ss += __shfl_xor(ss, off);
    float scale = 1.0f / fmaxf(sqrtf(ss), 1e-12f);
    float x0 = v * scale;
    size_t o = (size_t)row * EMBED_DIM + lane;
    x0out[o] = x0;
    y0[o] = __bfloat16_as_ushort(__float2bfloat16(x0 * dinv[row]));
}

// ---------------------------------------------------------------------------
// pull-mode propagation (round-3 v4 structure — best measured): NPW(4)
// nodes/wave, GUARD-FREE pad-16 inner loop, 4 independent uint2 gathers per
// iteration, pair pointer advances j += 16 across node boundaries.
// State is y = dinv*x; CSR holds RAW w; store applies node-uniform dinv^2.
// Prefetch overruns <=20 pairs past padded end (zeroed 64-pair tail).
// ---------------------------------------------------------------------------
#define BF_LO(u) __uint_as_float((u) << 16)
#define BF_HI(u) __uint_as_float((u) & 0xffff0000u)

__global__ void propagate_mid(const int* __restrict__ row_ptr,
                              const int2* __restrict__ csr_pair,
                              const float* __restrict__ dinv2,
                              const unsigned short* __restrict__ yin,
                              unsigned short* __restrict__ yout) {
    int wave = (blockIdx.x * blockDim.x + threadIdx.x) >> 6;
    int lane = threadIdx.x & 63;
    int node0 = wave * NPW;
    if (node0 >= N_NODES) return;

    int eg = lane >> 4;          // edge slot 0..3 (owns 4 consecutive edges)
    int dq = (lane & 15) << 2;   // dim quad start

    int rpv = row_ptr[node0 + (lane <= NPW ? lane : NPW)];
    int rs0 = __shfl(rpv, 0);
    int rs1 = __shfl(rpv, 1);
    int rs2 = __shfl(rpv, 2);
    int rs3 = __shfl(rpv, 3);
    int rs4 = __shfl(rpv, 4);

    int j = rs0 + (eg << 2);
    int2 pa0 = csr_pair[j];
    int2 pa1 = csr_pair[j + 1];
    int2 pa2 = csr_pair[j + 2];
    int2 pa3 = csr_pair[j + 3];

#pragma unroll
    for (int k = 0; k < NPW; ++k) {
        int bs = (k == 0) ? rs0 : (k == 1) ? rs1 : (k == 2) ? rs2 : rs3;
        int be = (k == 0) ? rs1 : (k == 1) ? rs2 : (k == 2) ? rs3 : rs4;
        float a0 = 0, a1 = 0, a2 = 0, a3 = 0;

        for (int base = bs; base < be; base += 16) {
            int   s0 = pa0.x; float w0 = __int_as_float(pa0.y);
            int   s1 = pa1.x; float w1 = __int_as_float(pa1.y);
            int   s2 = pa2.x; float w2 = __int_as_float(pa2.y);
            int   s3 = pa3.x; float w3 = __int_as_float(pa3.y);

            uint2 u0 = *(const uint2*)(yin + ((size_t)s0 << 6) + dq);
            uint2 u1 = *(const uint2*)(yin + ((size_t)s1 << 6) + dq);
            uint2 u2 = *(const uint2*)(yin + ((size_t)s2 << 6) + dq);
            uint2 u3 = *(const uint2*)(yin + ((size_t)s3 << 6) + dq);

            j += 16;                       // contiguous: always next group
            pa0 = csr_pair[j];
            pa1 = csr_pair[j + 1];
            pa2 = csr_pair[j + 2];
            pa3 = csr_pair[j + 3];

            a0 = fmaf(w0, BF_LO(u0.x), a0); a1 = fmaf(w0, BF_HI(u0.x), a1);
            a2 = fmaf(w0, BF_LO(u0.y), a2); a3 = fmaf(w0, BF_HI(u0.y), a3);
            a0 = fmaf(w1, BF_LO(u1.x), a0); a1 = fmaf(w1, BF_HI(u1.x), a1);
            a2 = fmaf(w1, BF_LO(u1.y), a2); a3 = fmaf(w1, BF_HI(u1.y), a3);
            a0 = fmaf(w2, BF_LO(u2.x), a0); a1 = fmaf(w2, BF_HI(u2.x), a1);
            a2 = fmaf(w2, BF_LO(u2.y), a2); a3 = fmaf(w2, BF_HI(u2.y), a3);
            a0 = fmaf(w3, BF_LO(u3.x), a0); a1 = fmaf(w3, BF_HI(u3.x), a1);
            a2 = fmaf(w3, BF_LO(u3.y), a2); a3 = fmaf(w3, BF_HI(u3.y), a3);
        }

        a0 += __shfl_xor(a0, 16); a1 += __shfl_xor(a1, 16);
        a2 += __shfl_xor(a2, 16); a3 += __shfl_xor(a3, 16);
        a0 += __shfl_xor(a0, 32); a1 += __shfl_xor(a1, 32);
        a2 += __shfl_xor(a2, 32); a3 += __shfl_xor(a3, 32);

        if (eg == 0) {
            float dc2 = dinv2[node0 + k];   // node-uniform, L2-hot
            size_t o = ((size_t)(node0 + k) << 6) + dq;
            unsigned int b0 = (unsigned int)__bfloat16_as_ushort(__float2bfloat16(a0 * dc2));
            unsigned int b1 = (unsigned int)__bfloat16_as_ushort(__float2bfloat16(a1 * dc2));
            unsigned int b2 = (unsigned int)__bfloat16_as_ushort(__float2bfloat16(a2 * dc2));
            unsigned int b3 = (unsigned int)__bfloat16_as_ushort(__float2bfloat16(a3 * dc2));
            uint2 u;
            u.x = b0 | (b1 << 16);
            u.y = b2 | (b3 << 16);
            *(uint2*)(yout + o) = u;
        }
    }
}

// ---------------------------------------------------------------------------
// FINAL layer: a = sum w*y2[src]; x3 = dinv*a; merge with x0 (f32, parked in
// outp) and x1 = rd*y1, x2 = rd*y2; l2norm; overwrite outp.
// ---------------------------------------------------------------------------
__global__ void propagate_final(const int* __restrict__ row_ptr,
                                const int2* __restrict__ csr_pair,
                                const float* __restrict__ dinv,
                                const float* __restrict__ rd,
                                const unsigned short* __restrict__ y1,
                                const unsigned short* __restrict__ y2,
                                float* __restrict__ outp) {
    int wave = (blockIdx.x * blockDim.x + threadIdx.x) >> 6;
    int lane = threadIdx.x & 63;
    int node0 = wave * NPW;
    if (node0 >= N_NODES) return;

    int eg = lane >> 4;
    int dq = (lane & 15) << 2;

    int rpv = row_ptr[node0 + (lane <= NPW ? lane : NPW)];
    int rs0 = __shfl(rpv, 0);
    int rs1 = __shfl(rpv, 1);
    int rs2 = __shfl(rpv, 2);
    int rs3 = __shfl(rpv, 3);
    int rs4 = __shfl(rpv, 4);

    int j = rs0 + (eg << 2);
    int2 pa0 = csr_pair[j];
    int2 pa1 = csr_pair[j + 1];
    int2 pa2 = csr_pair[j + 2];
    int2 pa3 = csr_pair[j + 3];

#pragma unroll
    for (int k = 0; k < NPW; ++k) {
        int bs = (k == 0) ? rs0 : (k == 1) ? rs1 : (k == 2) ? rs2 : rs3;
        int be = (k == 0) ? rs1 : (k == 1) ? rs2 : (k == 2) ? rs3 : rs4;
        float a0 = 0, a1 = 0, a2 = 0, a3 = 0;

        for (int base = bs; base < be; base += 16) {
            int   s0 = pa0.x; float w0 = __int_as_float(pa0.y);
            int   s1 = pa1.x; float w1 = __int_as_float(pa1.y);
            int   s2 = pa2.x; float w2 = __int_as_float(pa2.y);
            int   s3 = pa3.x; float w3 = __int_as_float(pa3.y);

            uint2 u0 = *(const uint2*)(y2 + ((size_t)s0 << 6) + dq);
            uint2 u1 = *(const uint2*)(y2 + ((size_t)s1 << 6) + dq);
            uint2 u2 = *(const uint2*)(y2 + ((size_t)s2 << 6) + dq);
            uint2 u3 = *(const uint2*)(y2 + ((size_t)s3 << 6) + dq);

            j += 16;
            pa0 = csr_pair[j];
            pa1 = csr_pair[j + 1];
            pa2 = csr_pair[j + 2];
            pa3 = csr_pair[j + 3];

            a0 = fmaf(w0, BF_LO(u0.x), a0); a1 = fmaf(w0, BF_HI(u0.x), a1);
            a2 = fmaf(w0, BF_LO(u0.y), a2); a3 = fmaf(w0, BF_HI(u0.y), a3);
            a0 = fmaf(w1, BF_LO(u1.x), a0); a1 = fmaf(w1, BF_HI(u1.x), a1);
            a2 = fmaf(w1, BF_LO(u1.y), a2); a3 = fmaf(w1, BF_HI(u1.y), a3);
            a0 = fmaf(w2, BF_LO(u2.x), a0); a1 = fmaf(w2, BF_HI(u2.x), a1);
            a2 = fmaf(w2, BF_LO(u2.y), a2); a3 = fmaf(w2, BF_HI(u2.y), a3);
            a0 = fmaf(w3, BF_LO(u3.x), a0); a1 = fmaf(w3, BF_HI(u3.x), a1);
            a2 = fmaf(w3, BF_LO(u3.y), a2); a3 = fmaf(w3, BF_HI(u3.y), a3);
        }

        a0 += __shfl_xor(a0, 16); a1 += __shfl_xor(a1, 16);
        a2 += __shfl_xor(a2, 16); a3 += __shfl_xor(a3, 16);
        a0 += __shfl_xor(a0, 32); a1 += __shfl_xor(a1, 32);
        a2 += __shfl_xor(a2, 32); a3 += __shfl_xor(a3, 32);

        if (eg == 0) {
            int node = node0 + k;
            float dv  = dinv[node];
            float rdv = rd[node];
            size_t o = ((size_t)node << 6) + dq;
            float4 x0v = *(const float4*)(outp + o);
            uint2 u1v = *(const uint2*)(y1 + o);
            uint2 u2v = *(const uint2*)(y2 + o);

            float v0 = (x0v.x + rdv * (BF_LO(u1v.x) + BF_LO(u2v.x)) + dv * a0) * 0.25f;
            float v1 = (x0v.y + rdv * (BF_HI(u1v.x) + BF_HI(u2v.x)) + dv * a1) * 0.25f;
            float v2 = (x0v.z + rdv * (BF_LO(u1v.y) + BF_LO(u2v.y)) + dv * a2) * 0.25f;
            float v3 = (x0v.w + rdv * (BF_HI(u1v.y) + BF_HI(u2v.y)) + dv * a3) * 0.25f;

            float ss = v0 * v0 + v1 * v1 + v2 * v2 + v3 * v3;
            ss += __shfl_xor(ss, 1);
            ss += __shfl_xor(ss, 2);
            ss += __shfl_xor(ss, 4);
            ss += __shfl_xor(ss, 8);
            float scale = 1.0f / fmaxf(sqrtf(ss), 1e-12f);

            float4 r = { v0 * scale, v1 * scale, v2 * scale, v3 * scale };
            *(float4*)(outp + o) = r;
        }
    }
    if (blockIdx.x == 0 && threadIdx.x == 0)
        outp[(size_t)N_NODES * EMBED_DIM] = 0.0f;  // align_loss
}

#undef BF_LO
#undef BF_HI

// ---------------------------------------------------------------------------
extern "C" void kernel_launch(void* const* d_in, const int* in_sizes, int n_in,
                              void* d_out, int out_size, void* d_ws, size_t ws_size,
                              hipStream_t stream) {
    const float* user_w     = (const float*)d_in[0];
    const float* artist_w   = (const float*)d_in[1];
    const float* album_w    = (const float*)d_in[2];
    const float* audio      = (const float*)d_in[3];
    const float* edge_attr  = (const float*)d_in[4];
    const float* ew         = (const float*)d_in[5];
    const float* w1         = (const float*)d_in[6];
    const float* b1         = (const float*)d_in[7];
    const float* w2         = (const float*)d_in[8];
    const float* b2         = (const float*)d_in[9];
    const int*   edge_index = (const int*)d_in[10];
    const int*   artist_ids = (const int*)d_in[11];
    const int*   album_ids  = (const int*)d_in[12];
    float* out = (float*)d_out;

    float* ws = (float*)d_ws;
    // Persistent regions (float-unit offsets):
    unsigned short* y0 = (unsigned short*)ws;                // 9.6M bf16
    unsigned short* y1 = (unsigned short*)(ws + 4800000);    // 9.6M bf16
    unsigned short* y2 = (unsigned short*)(ws + 9600000);    // 9.6M bf16
    float* dinv    = ws + 14400000;                          // 150k floats
    float* dinv2   = ws + 14560000;                          // 150k floats
    float* rd      = ws + 14720000;                          // 150k floats
    int*  row_ptr  = (int*)(ws + 14880000);                  // 150001 ints
    int*  wp       = (int*)(ws + 15040000);                  // 150k ints
    int2* csr_pair = (int2*)(ws + 15200000);                 // padded-16 CSR
                                                             // (+64 tail)
    // Transients aliased into y0 region (dead before init_x):
    int*   cnt     = (int*)ws;                               // 150k ints
    int*   part    = (int*)(ws + 200000);                    // 147 ints
    int*   baseoff = (int*)(ws + 201000);                    // 147 ints

    const int B = 256;
    const int egrid   = (NUM_EDGES + B - 1) / B;             // 1 edge/thread
    const int egrid4  = (NUM_EDGES / 4 + B - 1) / B;         // 4 edges/thread
    const int ngrid   = (N_NODES * EMBED_DIM) / B;           // wave-per-node
    const int ngrid16 = (N_NODES * 16) / B;                  // 16-lane-per-node
    const int pgrid   = (N_NODES / NPW * 64) / B;            // NPW-nodes-per-wave

    hipMemsetAsync(cnt, 0, N_NODES * sizeof(int), stream);

    count4<<<egrid4, B, 0, stream>>>(edge_index, cnt);

    scan_partial<<<SCAN_NB, SCAN_B, 0, stream>>>(cnt, part);
    scan_offsets<<<1, 256, 0, stream>>>(part, baseoff);
    scan_apply<<<SCAN_NB, SCAN_B, 0, stream>>>(cnt, baseoff, row_ptr, wp);

    mlp_scatter<<<egrid, B, 0, stream>>>(
        edge_attr, ew, w1, b1, w2, b2, edge_index, wp, csr_pair);

    degpad<<<ngrid16, B, 0, stream>>>(
        row_ptr, cnt, csr_pair, dinv, dinv2, rd);

    init_x<<<ngrid, B, 0, stream>>>(
        user_w, artist_w, album_w, audio, artist_ids, album_ids,
        dinv, out, y0);

    propagate_mid<<<pgrid, B, 0, stream>>>(row_ptr, csr_pair, dinv2, y0, y1);
    propagate_mid<<<pgrid, B, 0, stream>>>(row_ptr, csr_pair, dinv2, y1, y2);
    propagate_final<<<pgrid, B, 0, stream>>>(row_ptr, csr_pair, dinv, rd, y1, y2, out);
}

// Round 10
// 389.701 us; speedup vs baseline: 1.1093x; 1.1093x over previous
//
#include <hip/hip_runtime.h>
#include <hip/hip_bf16.h>
#include <math.h>

#define NUM_USERS  100000
#define NUM_ITEMS  50000
#define N_NODES    150000
#define EMBED_DIM  64
#define NUM_EDGES  1250000
#define MLP_HID    32
#define SCAN_B     1024
#define SCAN_NB    ((N_NODES + SCAN_B - 1) / SCAN_B)   // 147
#define NPW        4                                   // nodes per wave
#define PAD(x)     (((x) + 15) & ~15)                  // segment pad to 16

// ---------------------------------------------------------------------------
// hist + per-edge MLP fused; XCD-SHARDED counters: shard = blockIdx & 7.
// Workgroups round-robin across XCDs, so shard s's lines live in XCD s's L2
// -> the return-atomic executes locally instead of bouncing on the fabric.
// rank[e] packs {shard(3b) | local_rank(28b)}.  epair[e]={src,w} streaming.
// ---------------------------------------------------------------------------
__global__ void hist_mlp(const float* __restrict__ edge_attr,
                         const float* __restrict__ ew,
                         const float* __restrict__ w1,
                         const float* __restrict__ b1,
                         const float* __restrict__ w2,
                         const float* __restrict__ b2,
                         const int*   __restrict__ edge_index,
                         int*   __restrict__ cnt8,
                         int*   __restrict__ rank,
                         int2*  __restrict__ epair) {
    __shared__ float w1s[8 * MLP_HID];
    __shared__ float b1s[MLP_HID];
    __shared__ float w2s[MLP_HID];
    int tid = threadIdx.x;
    if (tid < 8 * MLP_HID) w1s[tid] = w1[tid];
    if (tid < MLP_HID) { b1s[tid] = b1[tid]; w2s[tid] = w2[tid]; }
    __syncthreads();

    int e = blockIdx.x * blockDim.x + tid;
    if (e >= NUM_EDGES) return;

    int sh = blockIdx.x & 7;
    int c = edge_index[NUM_EDGES + e];
    int lr = atomicAdd(&cnt8[sh * N_NODES + c], 1);   // XCD-local RMW

    float ef[8];
#pragma unroll
    for (int k = 0; k < 7; ++k) ef[k] = edge_attr[e * 7 + k];
    ef[7] = ew[e];

    float s = b2[0];
#pragma unroll
    for (int j = 0; j < MLP_HID; ++j) {
        float h = b1s[j];
#pragma unroll
        for (int k = 0; k < 8; ++k) h = fmaf(ef[k], w1s[k * MLP_HID + j], h);
        h = fmaxf(h, 0.0f);
        s = fmaf(h, w2s[j], s);
    }
    float w = 1.0f / (1.0f + expf(-s));

    rank[e] = lr | (sh << 28);
    int2 pr;
    pr.x = edge_index[e];          // src row
    pr.y = __float_as_int(w);      // RAW weight
    epair[e] = pr;                 // streaming, coalesced
}

// ---------------------------------------------------------------------------
// Per-node: turn 8 shard counts into shard-exclusive prefixes (in place) and
// the total cnt[n].  8 coalesced strided passes, ~5MB R/W.
// ---------------------------------------------------------------------------
__global__ void reduce8(int* __restrict__ cnt8,
                        int* __restrict__ cnt) {
    int n = blockIdx.x * blockDim.x + threadIdx.x;
    if (n >= N_NODES) return;
    int acc = 0;
#pragma unroll
    for (int s = 0; s < 8; ++s) {
        int c = cnt8[s * N_NODES + n];
        cnt8[s * N_NODES + n] = acc;   // exclusive prefix
        acc += c;
    }
    cnt[n] = acc;
}

// ---------------------------------------------------------------------------
// Device-wide exclusive scan of PAD16(cnt) -> row_ptr, 3 phases.
// ---------------------------------------------------------------------------
__global__ void scan_partial(const int* __restrict__ cnt,
                             int* __restrict__ part) {
    __shared__ int s[SCAN_B];
    int tid = threadIdx.x;
    int i = blockIdx.x * SCAN_B + tid;
    s[tid] = (i < N_NODES) ? PAD(cnt[i]) : 0;
    __syncthreads();
#pragma unroll
    for (int off = SCAN_B / 2; off > 0; off >>= 1) {
        if (tid < off) s[tid] += s[tid + off];
        __syncthreads();
    }
    if (tid == 0) part[blockIdx.x] = s[0];
}

__global__ void scan_offsets(const int* __restrict__ part,
                             int* __restrict__ base_off) {
    __shared__ int s[256];
    int tid = threadIdx.x;
    int v = (tid < SCAN_NB) ? part[tid] : 0;
    s[tid] = v;
    __syncthreads();
#pragma unroll
    for (int off = 1; off < 256; off <<= 1) {
        int t = (tid >= off) ? s[tid - off] : 0;
        __syncthreads();
        s[tid] += t;
        __syncthreads();
    }
    if (tid < SCAN_NB) base_off[tid] = s[tid] - v;   // exclusive
}

__global__ void scan_apply(const int* __restrict__ cnt,
                           const int* __restrict__ base_off,
                           int* __restrict__ row_ptr) {
    __shared__ int s[SCAN_B];
    int tid = threadIdx.x;
    int i = blockIdx.x * SCAN_B + tid;
    int v = (i < N_NODES) ? PAD(cnt[i]) : 0;
    s[tid] = v;
    __syncthreads();
    for (int off = 1; off < SCAN_B; off <<= 1) {
        int t = (tid >= off) ? s[tid - off] : 0;
        __syncthreads();
        s[tid] += t;
        __syncthreads();
    }
    if (i < N_NODES) row_ptr[i] = s[tid] - v + base_off[blockIdx.x];
    if (i == N_NODES - 1) row_ptr[N_NODES] = s[tid] + base_off[blockIdx.x];
}

// ---------------------------------------------------------------------------
// perm[row_ptr[c] + pref8[s][c] + lr] = e   — 4 edges/thread.
// Two L2-hot random 4B gathers (row_ptr, cnt8 prefix) + one 4B scatter.
// ---------------------------------------------------------------------------
__global__ void scatter_perm(const int* __restrict__ edge_index,
                             const int* __restrict__ rank,
                             const int* __restrict__ row_ptr,
                             const int* __restrict__ cnt8,
                             int* __restrict__ perm) {
    int t = blockIdx.x * blockDim.x + threadIdx.x;
    int e = 4 * t;                  // NUM_EDGES % 4 == 0
    if (e >= NUM_EDGES) return;
    int4 cc = *(const int4*)(edge_index + NUM_EDGES + e);
    int4 rr = *(const int4*)(rank + e);
    int cs[4] = { cc.x, cc.y, cc.z, cc.w };
    int rs[4] = { rr.x, rr.y, rr.z, rr.w };
#pragma unroll
    for (int q = 0; q < 4; ++q) {
        int c  = cs[q];
        int sh = rs[q] >> 28;
        int lr = rs[q] & 0x0FFFFFFF;
        int pref = cnt8[sh * N_NODES + c];
        perm[row_ptr[c] + pref + lr] = e + q;
    }
}

// ---------------------------------------------------------------------------
// FUSED: build padded CSR in gather mode + deg->dinv/dinv2/rd + init phase
// (x0 f32 into OUTPUT buffer, y0 = dinv*x0 bf16).  The init streaming work
// fills the latency bubbles of the random perm/epair gathers.
// 16 lanes/node; lane l owns dims [4l,4l+4).
// ---------------------------------------------------------------------------
__global__ void pair_build_init(const int* __restrict__ row_ptr,
                                const int* __restrict__ cnt,
                                const int* __restrict__ perm,
                                const int2* __restrict__ epair,
                                const float* __restrict__ user_w,
                                const float* __restrict__ artist_w,
                                const float* __restrict__ album_w,
                                const float* __restrict__ audio,
                                const int*   __restrict__ artist_ids,
                                const int*   __restrict__ album_ids,
                                int2* __restrict__ csr_pair,
                                float* __restrict__ dinv,
                                float* __restrict__ dinv2,
                                float* __restrict__ rd,
                                float* __restrict__ x0out,
                                unsigned short* __restrict__ y0) {
    int t = blockIdx.x * blockDim.x + threadIdx.x;
    int node = t >> 4;
    int lane = t & 15;
    if (node >= N_NODES) return;
    int s = row_ptr[node];
    int e = row_ptr[node + 1];
    int re = s + cnt[node];

    // ---- phase 1: CSR build (raw w) + segment sum ----
    float sum = 0.0f;
    for (int j = s + lane; j < e; j += 16) {
        int2 pr;
        if (j < re) {
            int eid = perm[j];
            pr = epair[eid];
            sum += __int_as_float(pr.y);
        } else {
            pr.x = 0; pr.y = 0;
        }
        csr_pair[j] = pr;
    }
    sum += __shfl_xor(sum, 8);
    sum += __shfl_xor(sum, 4);
    sum += __shfl_xor(sum, 2);
    sum += __shfl_xor(sum, 1);
    float dv = (sum > 0.0f) ? rsqrtf(fmaxf(sum, 1e-30f)) : 0.0f;
    if (lane == 0) {
        dinv[node]  = dv;
        dinv2[node] = dv * dv;
        rd[node]    = (dv > 0.0f) ? (1.0f / dv) : 0.0f;
    }
    if (node == N_NODES - 1) {
        int2 z; z.x = 0; z.y = 0;
        for (int q = lane; q < 64; q += 16) csr_pair[e + q] = z;
    }

    // ---- phase 2: init x0 (f32 -> out) and y0 = dv*x0 (bf16) ----
    float4 v;
    if (node < NUM_USERS) {
        v = *(const float4*)(user_w + (size_t)node * EMBED_DIM + lane * 4);
    } else {
        int r = node - NUM_USERS;
        int ar = artist_ids[r];
        int al = album_ids[r];
        float4 a  = *(const float4*)(audio    + (size_t)r  * EMBED_DIM + lane * 4);
        float4 b  = *(const float4*)(artist_w + (size_t)ar * EMBED_DIM + lane * 4);
        float4 cl = *(const float4*)(album_w  + (size_t)al * EMBED_DIM + lane * 4);
        v.x = a.x + 0.5f * (b.x + cl.x);
        v.y = a.y + 0.5f * (b.y + cl.y);
        v.z = a.z + 0.5f * (b.z + cl.z);
        v.w = a.w + 0.5f * (b.w + cl.w);
    }
    float ss = v.x * v.x + v.y * v.y + v.z * v.z + v.w * v.w;
    ss += __shfl_xor(ss, 1);
    ss += __shfl_xor(ss, 2);
    ss += __shfl_xor(ss, 4);
    ss += __shfl_xor(ss, 8);
    float scale = 1.0f / fmaxf(sqrtf(ss), 1e-12f);
    float4 x0;
    x0.x = v.x * scale; x0.y = v.y * scale;
    x0.z = v.z * scale; x0.w = v.w * scale;
    size_t o = ((size_t)node << 6) + lane * 4;
    *(float4*)(x0out + o) = x0;
    unsigned int b0 = (unsigned int)__bfloat16_as_ushort(__float2bfloat16(x0.x * dv));
    unsigned int b1 = (unsigned int)__bfloat16_as_ushort(__float2bfloat16(x0.y * dv));
    unsigned int b2 = (unsigned int)__bfloat16_as_ushort(__float2bfloat16(x0.z * dv));
    unsigned int b3 = (unsigned int)__bfloat16_as_ushort(__float2bfloat16(x0.w * dv));
    uint2 u;
    u.x = b0 | (b1 << 16);
    u.y = b2 | (b3 << 16);
    *(uint2*)(y0 + o) = u;
}

// ---------------------------------------------------------------------------
// pull-mode propagation (round-3/8 structure, measured best): NPW(4)
// nodes/wave, guard-free pad-16 loop, 4 independent uint2 gathers/iter.
// State y = dinv*x; CSR holds RAW w; store applies node-uniform dinv^2.
// ---------------------------------------------------------------------------
#define BF_LO(u) __uint_as_float((u) << 16)
#define BF_HI(u) __uint_as_float((u) & 0xffff0000u)

__global__ void propagate_mid(const int* __restrict__ row_ptr,
                              const int2* __restrict__ csr_pair,
                              const float* __restrict__ dinv2,
                              const unsigned short* __restrict__ yin,
                              unsigned short* __restrict__ yout) {
    int wave = (blockIdx.x * blockDim.x + threadIdx.x) >> 6;
    int lane = threadIdx.x & 63;
    int node0 = wave * NPW;
    if (node0 >= N_NODES) return;

    int eg = lane >> 4;
    int dq = (lane & 15) << 2;

    int rpv = row_ptr[node0 + (lane <= NPW ? lane : NPW)];
    int rs0 = __shfl(rpv, 0);
    int rs1 = __shfl(rpv, 1);
    int rs2 = __shfl(rpv, 2);
    int rs3 = __shfl(rpv, 3);
    int rs4 = __shfl(rpv, 4);

    int j = rs0 + (eg << 2);
    int2 pa0 = csr_pair[j];
    int2 pa1 = csr_pair[j + 1];
    int2 pa2 = csr_pair[j + 2];
    int2 pa3 = csr_pair[j + 3];

#pragma unroll
    for (int k = 0; k < NPW; ++k) {
        int bs = (k == 0) ? rs0 : (k == 1) ? rs1 : (k == 2) ? rs2 : rs3;
        int be = (k == 0) ? rs1 : (k == 1) ? rs2 : (k == 2) ? rs3 : rs4;
        float a0 = 0, a1 = 0, a2 = 0, a3 = 0;

        for (int base = bs; base < be; base += 16) {
            int   s0 = pa0.x; float w0 = __int_as_float(pa0.y);
            int   s1 = pa1.x; float w1 = __int_as_float(pa1.y);
            int   s2 = pa2.x; float w2 = __int_as_float(pa2.y);
            int   s3 = pa3.x; float w3 = __int_as_float(pa3.y);

            uint2 u0 = *(const uint2*)(yin + ((size_t)s0 << 6) + dq);
            uint2 u1 = *(const uint2*)(yin + ((size_t)s1 << 6) + dq);
            uint2 u2 = *(const uint2*)(yin + ((size_t)s2 << 6) + dq);
            uint2 u3 = *(const uint2*)(yin + ((size_t)s3 << 6) + dq);

            j += 16;
            pa0 = csr_pair[j];
            pa1 = csr_pair[j + 1];
            pa2 = csr_pair[j + 2];
            pa3 = csr_pair[j + 3];

            a0 = fmaf(w0, BF_LO(u0.x), a0); a1 = fmaf(w0, BF_HI(u0.x), a1);
            a2 = fmaf(w0, BF_LO(u0.y), a2); a3 = fmaf(w0, BF_HI(u0.y), a3);
            a0 = fmaf(w1, BF_LO(u1.x), a0); a1 = fmaf(w1, BF_HI(u1.x), a1);
            a2 = fmaf(w1, BF_LO(u1.y), a2); a3 = fmaf(w1, BF_HI(u1.y), a3);
            a0 = fmaf(w2, BF_LO(u2.x), a0); a1 = fmaf(w2, BF_HI(u2.x), a1);
            a2 = fmaf(w2, BF_LO(u2.y), a2); a3 = fmaf(w2, BF_HI(u2.y), a3);
            a0 = fmaf(w3, BF_LO(u3.x), a0); a1 = fmaf(w3, BF_HI(u3.x), a1);
            a2 = fmaf(w3, BF_LO(u3.y), a2); a3 = fmaf(w3, BF_HI(u3.y), a3);
        }

        a0 += __shfl_xor(a0, 16); a1 += __shfl_xor(a1, 16);
        a2 += __shfl_xor(a2, 16); a3 += __shfl_xor(a3, 16);
        a0 += __shfl_xor(a0, 32); a1 += __shfl_xor(a1, 32);
        a2 += __shfl_xor(a2, 32); a3 += __shfl_xor(a3, 32);

        if (eg == 0) {
            float dc2 = dinv2[node0 + k];
            size_t o = ((size_t)(node0 + k) << 6) + dq;
            unsigned int b0 = (unsigned int)__bfloat16_as_ushort(__float2bfloat16(a0 * dc2));
            unsigned int b1 = (unsigned int)__bfloat16_as_ushort(__float2bfloat16(a1 * dc2));
            unsigned int b2 = (unsigned int)__bfloat16_as_ushort(__float2bfloat16(a2 * dc2));
            unsigned int b3 = (unsigned int)__bfloat16_as_ushort(__float2bfloat16(a3 * dc2));
            uint2 u;
            u.x = b0 | (b1 << 16);
            u.y = b2 | (b3 << 16);
            *(uint2*)(yout + o) = u;
        }
    }
}

// ---------------------------------------------------------------------------
// FINAL layer: a = sum w*y2[src]; x3 = dinv*a; merge with x0 (f32 in outp),
// x1 = rd*y1, x2 = rd*y2; l2norm; overwrite outp.
// ---------------------------------------------------------------------------
__global__ void propagate_final(const int* __restrict__ row_ptr,
                                const int2* __restrict__ csr_pair,
                                const float* __restrict__ dinv,
                                const float* __restrict__ rd,
                                const unsigned short* __restrict__ y1,
                                const unsigned short* __restrict__ y2,
                                float* __restrict__ outp) {
    int wave = (blockIdx.x * blockDim.x + threadIdx.x) >> 6;
    int lane = threadIdx.x & 63;
    int node0 = wave * NPW;
    if (node0 >= N_NODES) return;

    int eg = lane >> 4;
    int dq = (lane & 15) << 2;

    int rpv = row_ptr[node0 + (lane <= NPW ? lane : NPW)];
    int rs0 = __shfl(rpv, 0);
    int rs1 = __shfl(rpv, 1);
    int rs2 = __shfl(rpv, 2);
    int rs3 = __shfl(rpv, 3);
    int rs4 = __shfl(rpv, 4);

    int j = rs0 + (eg << 2);
    int2 pa0 = csr_pair[j];
    int2 pa1 = csr_pair[j + 1];
    int2 pa2 = csr_pair[j + 2];
    int2 pa3 = csr_pair[j + 3];

#pragma unroll
    for (int k = 0; k < NPW; ++k) {
        int bs = (k == 0) ? rs0 : (k == 1) ? rs1 : (k == 2) ? rs2 : rs3;
        int be = (k == 0) ? rs1 : (k == 1) ? rs2 : (k == 2) ? rs3 : rs4;
        float a0 = 0, a1 = 0, a2 = 0, a3 = 0;

        for (int base = bs; base < be; base += 16) {
            int   s0 = pa0.x; float w0 = __int_as_float(pa0.y);
            int   s1 = pa1.x; float w1 = __int_as_float(pa1.y);
            int   s2 = pa2.x; float w2 = __int_as_float(pa2.y);
            int   s3 = pa3.x; float w3 = __int_as_float(pa3.y);

            uint2 u0 = *(const uint2*)(y2 + ((size_t)s0 << 6) + dq);
            uint2 u1 = *(const uint2*)(y2 + ((size_t)s1 << 6) + dq);
            uint2 u2 = *(const uint2*)(y2 + ((size_t)s2 << 6) + dq);
            uint2 u3 = *(const uint2*)(y2 + ((size_t)s3 << 6) + dq);

            j += 16;
            pa0 = csr_pair[j];
            pa1 = csr_pair[j + 1];
            pa2 = csr_pair[j + 2];
            pa3 = csr_pair[j + 3];

            a0 = fmaf(w0, BF_LO(u0.x), a0); a1 = fmaf(w0, BF_HI(u0.x), a1);
            a2 = fmaf(w0, BF_LO(u0.y), a2); a3 = fmaf(w0, BF_HI(u0.y), a3);
            a0 = fmaf(w1, BF_LO(u1.x), a0); a1 = fmaf(w1, BF_HI(u1.x), a1);
            a2 = fmaf(w1, BF_LO(u1.y), a2); a3 = fmaf(w1, BF_HI(u1.y), a3);
            a0 = fmaf(w2, BF_LO(u2.x), a0); a1 = fmaf(w2, BF_HI(u2.x), a1);
            a2 = fmaf(w2, BF_LO(u2.y), a2); a3 = fmaf(w2, BF_HI(u2.y), a3);
            a0 = fmaf(w3, BF_LO(u3.x), a0); a1 = fmaf(w3, BF_HI(u3.x), a1);
            a2 = fmaf(w3, BF_LO(u3.y), a2); a3 = fmaf(w3, BF_HI(u3.y), a3);
        }

        a0 += __shfl_xor(a0, 16); a1 += __shfl_xor(a1, 16);
        a2 += __shfl_xor(a2, 16); a3 += __shfl_xor(a3, 16);
        a0 += __shfl_xor(a0, 32); a1 += __shfl_xor(a1, 32);
        a2 += __shfl_xor(a2, 32); a3 += __shfl_xor(a3, 32);

        if (eg == 0) {
            int node = node0 + k;
            float dv  = dinv[node];
            float rdv = rd[node];
            size_t o = ((size_t)node << 6) + dq;
            float4 x0v = *(const float4*)(outp + o);
            uint2 u1v = *(const uint2*)(y1 + o);
            uint2 u2v = *(const uint2*)(y2 + o);

            float v0 = (x0v.x + rdv * (BF_LO(u1v.x) + BF_LO(u2v.x)) + dv * a0) * 0.25f;
            float v1 = (x0v.y + rdv * (BF_HI(u1v.x) + BF_HI(u2v.x)) + dv * a1) * 0.25f;
            float v2 = (x0v.z + rdv * (BF_LO(u1v.y) + BF_LO(u2v.y)) + dv * a2) * 0.25f;
            float v3 = (x0v.w + rdv * (BF_HI(u1v.y) + BF_HI(u2v.y)) + dv * a3) * 0.25f;

            float ss = v0 * v0 + v1 * v1 + v2 * v2 + v3 * v3;
            ss += __shfl_xor(ss, 1);
            ss += __shfl_xor(ss, 2);
            ss += __shfl_xor(ss, 4);
            ss += __shfl_xor(ss, 8);
            float scale = 1.0f / fmaxf(sqrtf(ss), 1e-12f);

            float4 r = { v0 * scale, v1 * scale, v2 * scale, v3 * scale };
            *(float4*)(outp + o) = r;
        }
    }
    if (blockIdx.x == 0 && threadIdx.x == 0)
        outp[(size_t)N_NODES * EMBED_DIM] = 0.0f;  // align_loss
}

#undef BF_LO
#undef BF_HI

// ---------------------------------------------------------------------------
extern "C" void kernel_launch(void* const* d_in, const int* in_sizes, int n_in,
                              void* d_out, int out_size, void* d_ws, size_t ws_size,
                              hipStream_t stream) {
    const float* user_w     = (const float*)d_in[0];
    const float* artist_w   = (const float*)d_in[1];
    const float* album_w    = (const float*)d_in[2];
    const float* audio      = (const float*)d_in[3];
    const float* edge_attr  = (const float*)d_in[4];
    const float* ew         = (const float*)d_in[5];
    const float* w1         = (const float*)d_in[6];
    const float* b1         = (const float*)d_in[7];
    const float* w2         = (const float*)d_in[8];
    const float* b2         = (const float*)d_in[9];
    const int*   edge_index = (const int*)d_in[10];
    const int*   artist_ids = (const int*)d_in[11];
    const int*   album_ids  = (const int*)d_in[12];
    float* out = (float*)d_out;

    float* ws = (float*)d_ws;
    // Persistent regions (float-unit offsets):
    unsigned short* y0 = (unsigned short*)ws;                // 9.6M bf16 (0..4.8M fl)
    unsigned short* y1 = (unsigned short*)(ws + 4800000);    // 9.6M bf16
    unsigned short* y2 = (unsigned short*)(ws + 9600000);    // 9.6M bf16
    float* dinv    = ws + 14400000;                          // 150k
    float* dinv2   = ws + 14560000;                          // 150k
    float* rd      = ws + 14720000;                          // 150k
    int*  row_ptr  = (int*)(ws + 14880000);                  // 150001
    int*  cnt      = (int*)(ws + 15040000);                  // 150k (totals)
    int*  cnt8     = (int*)(ws + 15200000);                  // 8 x 150k shards
    int*  part     = (int*)(ws + 16450000);                  // 147
    int*  baseoff  = (int*)(ws + 16451000);                  // 147
    int2* csr_pair = (int2*)(ws + 16500000);                 // padded-16 CSR
                                                             // (+64 tail)
    // Transients in y1/y2 regions (dead before mids write them):
    int2* epair = (int2*)(ws + 4800000);                     // 1.25M pairs (y1)
    int*  rank  = (int*)(ws + 9600000);                      // 1.25M ints  (y2)
    int*  perm  = (int*)(ws + 10850000);                     // <=2.5M ints (y2)

    const int B = 256;
    const int egrid   = (NUM_EDGES + B - 1) / B;             // 1 edge/thread
    const int egrid4  = (NUM_EDGES / 4 + B - 1) / B;         // 4 edges/thread
    const int ngrid16 = (N_NODES * 16) / B;                  // 16-lane-per-node
    const int dgrid   = (N_NODES + B - 1) / B;               // 1-thread-per-node
    const int pgrid   = (N_NODES / NPW * 64) / B;            // NPW-nodes-per-wave

    hipMemsetAsync(cnt8, 0, 8 * N_NODES * sizeof(int), stream);

    hist_mlp<<<egrid, B, 0, stream>>>(
        edge_attr, ew, w1, b1, w2, b2, edge_index, cnt8, rank, epair);

    reduce8<<<dgrid, B, 0, stream>>>(cnt8, cnt);

    scan_partial<<<SCAN_NB, SCAN_B, 0, stream>>>(cnt, part);
    scan_offsets<<<1, 256, 0, stream>>>(part, baseoff);
    scan_apply<<<SCAN_NB, SCAN_B, 0, stream>>>(cnt, baseoff, row_ptr);

    scatter_perm<<<egrid4, B, 0, stream>>>(
        edge_index, rank, row_ptr, cnt8, perm);

    pair_build_init<<<ngrid16, B, 0, stream>>>(
        row_ptr, cnt, perm, epair,
        user_w, artist_w, album_w, audio, artist_ids, album_ids,
        csr_pair, dinv, dinv2, rd, out, y0);

    propagate_mid<<<pgrid, B, 0, stream>>>(row_ptr, csr_pair, dinv2, y0, y1);
    propagate_mid<<<pgrid, B, 0, stream>>>(row_ptr, csr_pair, dinv2, y1, y2);
    propagate_final<<<pgrid, B, 0, stream>>>(row_ptr, csr_pair, dinv, rd, y1, y2, out);
}